// Round 14
// baseline (366.896 us; speedup 1.0000x reference)
//
#include <hip/hip_runtime.h>
#include <hip/hip_bf16.h>

#define NN 40000
#define NE 640000
#define NG 1000

typedef __attribute__((ext_vector_type(8))) short short8;
typedef __attribute__((ext_vector_type(4))) float f32x4;
typedef __attribute__((ext_vector_type(2))) __bf16 bf16x2v;

__device__ __forceinline__ float gelu_t(float x) {
    float u = 0.7978845608028654f * (x + 0.044715f * x * x * x);
    return 0.5f * x * (1.0f + tanhf(u));
}
__device__ __forceinline__ void atomAddF(float* p, float v) {
    unsafeAtomicAdd(p, v);
}
__device__ __forceinline__ int rfl(int v) { return __builtin_amdgcn_readfirstlane(v); }
__device__ __forceinline__ unsigned short f2bf(float f) {
    unsigned u = __float_as_uint(f);
    unsigned r = (u + 0x7fffu + ((u >> 16) & 1u)) >> 16;
    return (unsigned short)r;
}
__device__ __forceinline__ unsigned pk_bf(float lo, float hi) {
    __hip_bfloat162 v = __float22bfloat162_rn(make_float2(lo, hi));
    unsigned r;
    __builtin_memcpy(&r, &v, 4);
    return r;
}
__device__ __forceinline__ float bfl(unsigned p) { return __uint_as_float(p << 16); }
__device__ __forceinline__ float bfh(unsigned p) { return __uint_as_float(p & 0xffff0000u); }

__device__ __forceinline__ float dot2bf(unsigned a, unsigned b, float c) {
#if __has_builtin(__builtin_amdgcn_fdot2_f32_bf16)
    bf16x2v av, bv;
    __builtin_memcpy(&av, &a, 4);
    __builtin_memcpy(&bv, &b, 4);
    return __builtin_amdgcn_fdot2_f32_bf16(av, bv, c, false);
#else
    return c + bfl(a) * bfl(b) + bfh(a) * bfh(b);
#endif
}

// ---------------- Kernel P: x->bf16 + 8-way partitioned histogram + packs ----
__global__ __launch_bounds__(256) void k_pre(
    const float* __restrict__ x, const int* __restrict__ dst,
    const float* __restrict__ W_self, const float* __restrict__ W_msg,
    const float* __restrict__ W_e1, const float* __restrict__ b_msg,
    const float* __restrict__ b_e1,
    const float* __restrict__ W_l, const float* __restrict__ W_r,
    const float* __restrict__ W_e2,
    unsigned short* __restrict__ x_bf, int* __restrict__ hist,
    int* __restrict__ rank,
    unsigned short* __restrict__ wf1, unsigned short* __restrict__ wf2,
    unsigned* __restrict__ we2p, float* __restrict__ bsum2) {
    int t = blockIdx.x * 256 + threadIdx.x;
    float4 v = ((const float4*)x)[t];
    ((uint2*)x_bf)[t] = make_uint2(pk_bf(v.x, v.y), pk_bf(v.z, v.w));
    int part = t / 80000;           // 8 edge-range partitions
    rank[t] = atomicAdd(&hist[part * NN + dst[t]], 1);
    if (t < 256) bsum2[t] = b_msg[t] + b_e1[t];
    if (t < 5120) {
        int l = t & 63;
        int kt = (t >> 6) % 5;
        int gnt = t / 320;
        int n = gnt * 16 + (l & 15);
        int k0 = kt * 32 + (l >> 4) * 8;
        unsigned short vv[8];
        #pragma unroll
        for (int j = 0; j < 8; ++j) {
            int k = k0 + j;
            float wv;
            if (k < 64)       wv = W_self[(size_t)k * 256 + n];
            else if (k < 128) wv = W_msg[(size_t)(k - 64) * 256 + n];
            else if (k < 144) wv = W_e1[(size_t)(k - 128) * 256 + n];
            else              wv = 0.f;
            vv[j] = f2bf(wv);
        }
        uint4 pack;
        pack.x = (unsigned)vv[0] | ((unsigned)vv[1] << 16);
        pack.y = (unsigned)vv[2] | ((unsigned)vv[3] << 16);
        pack.z = (unsigned)vv[4] | ((unsigned)vv[5] << 16);
        pack.w = (unsigned)vv[6] | ((unsigned)vv[7] << 16);
        ((uint4*)wf1)[t] = pack;
    }
    if (t >= 5120 && t < 13312) {
        int t2 = t - 5120;
        int l = t2 & 63;
        int kt = (t2 >> 6) & 7;
        int gnt = t2 >> 9;
        int n = gnt * 16 + (l & 15);
        int k0 = kt * 32 + (l >> 4) * 8;
        const float* W = (n < 128) ? W_l : W_r;
        int nn = n & 127;
        float w[8];
        #pragma unroll
        for (int j = 0; j < 8; ++j) w[j] = W[(size_t)(k0 + j) * 128 + nn];
        uint4 pack;
        pack.x = pk_bf(w[0], w[1]);
        pack.y = pk_bf(w[2], w[3]);
        pack.z = pk_bf(w[4], w[5]);
        pack.w = pk_bf(w[6], w[7]);
        ((uint4*)wf2)[t2] = pack;
    }
    if (t >= 13312 && t < 14336) {
        int t3 = t - 13312;
        int tt = t3 >> 7;
        int c = t3 & 127;
        we2p[t3] = pk_bf(W_e2[(size_t)(2 * tt) * 128 + c],
                         W_e2[(size_t)(2 * tt + 1) * 128 + c]);
    }
}

// ---------------- CSR build: parallel degree sum (padded to 40960) -----------
__global__ __launch_bounds__(256) void k_dsum(const int* __restrict__ hist,
                                              int* __restrict__ dsum) {
    int idx = blockIdx.x * 256 + threadIdx.x;
    if (idx >= 40960) return;
    int s = 0;
    if (idx < NN) {
        #pragma unroll
        for (int p = 0; p < 8; ++p) s += hist[p * NN + idx];
    }
    dsum[idx] = s;
}

// ---------------- CSR build: single-block vectorized exclusive scan ----------
__global__ __launch_bounds__(1024) void k_scan(const int* __restrict__ dsum,
                                               int* __restrict__ row_ptr) {
    __shared__ int ssum[1024];
    int t = threadIdx.x;
    int base = t * 40;             // 1024*40 = 40960 exactly
    const int4* dv = (const int4*)(dsum + base);
    int local[40];
    int s = 0;
    #pragma unroll
    for (int j = 0; j < 10; ++j) {
        int4 v = dv[j];
        local[j * 4 + 0] = s; s += v.x;
        local[j * 4 + 1] = s; s += v.y;
        local[j * 4 + 2] = s; s += v.z;
        local[j * 4 + 3] = s; s += v.w;
    }
    ssum[t] = s;
    __syncthreads();
    for (int o = 1; o < 1024; o <<= 1) {
        int tmp = (t >= o) ? ssum[t - o] : 0;
        __syncthreads();
        ssum[t] += tmp;
        __syncthreads();
    }
    int prefix = (t > 0) ? ssum[t - 1] : 0;
    int4* rv = (int4*)(row_ptr + base);
    #pragma unroll
    for (int j = 0; j < 10; ++j) {
        int4 o4;
        o4.x = prefix + local[j * 4 + 0];
        o4.y = prefix + local[j * 4 + 1];
        o4.z = prefix + local[j * 4 + 2];
        o4.w = prefix + local[j * 4 + 3];
        rv[j] = o4;
    }
}

// ---------------- CSR build: per-partition offsets (parallel) ----------------
__global__ __launch_bounds__(256) void k_off(const int* __restrict__ hist,
                                             const int* __restrict__ row_ptr,
                                             int* __restrict__ off) {
    int idx = blockIdx.x * 256 + threadIdx.x;
    if (idx >= NN) return;
    int acc = row_ptr[idx];
    #pragma unroll
    for (int p = 0; p < 8; ++p) {
        off[p * NN + idx] = acc;
        acc += hist[p * NN + idx];
    }
}

// ---------------- CSR build: atomic-free scatter -----------------------------
__global__ __launch_bounds__(256) void k_scatter(const int* __restrict__ src,
                                                 const int* __restrict__ dst,
                                                 const int* __restrict__ rank,
                                                 const int* __restrict__ off,
                                                 const float* __restrict__ eattr,
                                                 int* __restrict__ csr_src,
                                                 unsigned short* __restrict__ ea_csr) {
    int e = blockIdx.x * 256 + threadIdx.x;
    if (e >= NE) return;
    int d = dst[e];
    int p = e / 80000;
    int pos = off[p * NN + d] + rank[e];
    csr_src[pos] = src[e];
    const float4* ep = (const float4*)(eattr + (size_t)e * 16);
    float4 a = ep[0], b = ep[1], c = ep[2], dd = ep[3];
    uint4 q0, q1;
    q0.x = pk_bf(a.x, a.y); q0.y = pk_bf(a.z, a.w);
    q0.z = pk_bf(b.x, b.y); q0.w = pk_bf(b.z, b.w);
    q1.x = pk_bf(c.x, c.y); q1.y = pk_bf(c.z, c.w);
    q1.z = pk_bf(dd.x, dd.y); q1.w = pk_bf(dd.z, dd.w);
    uint4* out = (uint4*)ea_csr;
    out[(size_t)pos * 2]     = q0;
    out[(size_t)pos * 2 + 1] = q1;
}

// ---------------- Kernel A: per-dst gather aggregation ----------------------
// x-gather: eighth-wave per edge (8 lanes x uint4 = 128B row), 16 rows in
// flight; ea: flat sequential dword stream.
__global__ __launch_bounds__(256) void k_agg(
    const unsigned short* __restrict__ x_bf, const unsigned short* __restrict__ ea_csr,
    const int* __restrict__ csr_src, const int* __restrict__ row_ptr,
    unsigned short* __restrict__ aggx_bf, unsigned short* __restrict__ aggea_bf,
    float* __restrict__ degf) {
    int d = rfl(blockIdx.x * 4 + (threadIdx.x >> 6));
    int lane = threadIdx.x & 63;
    if (d >= NN) return;
    int beg = rfl(row_ptr[d]), end = rfl(row_ptr[d + 1]);
    const uint4* xw4 = (const uint4*)x_bf;     // row = 8 uint4
    const unsigned* eaw = (const unsigned*)ea_csr;
    int oc = lane >> 3;       // octant 0..7
    int ol = lane & 7;        // cols [8*ol, 8*ol+8) as uint4
    float sa[8] = {};
    float sb[8] = {};
    int i = beg;
    for (; i + 15 < end; i += 16) {
        int sA = csr_src[i + oc];
        int sB = csr_src[i + 8 + oc];
        uint4 wA = xw4[(size_t)sA * 8 + ol];
        uint4 wB = xw4[(size_t)sB * 8 + ol];
        sa[0] += bfl(wA.x); sa[1] += bfh(wA.x); sa[2] += bfl(wA.y); sa[3] += bfh(wA.y);
        sa[4] += bfl(wA.z); sa[5] += bfh(wA.z); sa[6] += bfl(wA.w); sa[7] += bfh(wA.w);
        sb[0] += bfl(wB.x); sb[1] += bfh(wB.x); sb[2] += bfl(wB.y); sb[3] += bfh(wB.y);
        sb[4] += bfl(wB.z); sb[5] += bfh(wB.z); sb[6] += bfl(wB.w); sb[7] += bfh(wB.w);
    }
    for (; i < end; i += 8) {
        if (i + oc < end) {
            int s = csr_src[i + oc];
            uint4 w = xw4[(size_t)s * 8 + ol];
            sa[0] += bfl(w.x); sa[1] += bfh(w.x); sa[2] += bfl(w.y); sa[3] += bfh(w.y);
            sa[4] += bfl(w.z); sa[5] += bfh(w.z); sa[6] += bfl(w.w); sa[7] += bfh(w.w);
        }
    }
    float sx[8];
    #pragma unroll
    for (int j = 0; j < 8; ++j) {
        float v = sa[j] + sb[j];
        v += __shfl_xor(v, 8, 64);
        v += __shfl_xor(v, 16, 64);
        v += __shfl_xor(v, 32, 64);
        sx[j] = v;
    }
    // --- ea: flat sequential sum; uint p covers cols (2*(p&7), +1)
    float se0 = 0.f, se1 = 0.f, se0b = 0.f, se1b = 0.f;
    int p = beg * 8 + lane;
    int pend = end * 8;
    for (; p + 64 < pend; p += 128) {
        unsigned w = eaw[p];
        unsigned w2 = eaw[p + 64];
        se0 += bfl(w); se1 += bfh(w);
        se0b += bfl(w2); se1b += bfh(w2);
    }
    if (p < pend) {
        unsigned w = eaw[p];
        se0 += bfl(w); se1 += bfh(w);
    }
    se0 += se0b; se1 += se1b;
    #pragma unroll
    for (int off = 8; off < 64; off <<= 1) {
        se0 += __shfl_xor(se0, off, 64);
        se1 += __shfl_xor(se1, off, 64);
    }
    if (oc == 0) {
        uint4 o4;
        o4.x = pk_bf(sx[0], sx[1]); o4.y = pk_bf(sx[2], sx[3]);
        o4.z = pk_bf(sx[4], sx[5]); o4.w = pk_bf(sx[6], sx[7]);
        ((uint4*)aggx_bf)[(size_t)d * 8 + ol] = o4;
    }
    if (lane < 8) ((unsigned*)aggea_bf)[(size_t)d * 8 + lane] = pk_bf(se0, se1);
    if (lane == 0) degf[d] = (float)(end - beg);
}

// ---------------- Kernel HX: fused h-GEMM + xl/xr-GEMM (MFMA, LDS-staged) ----
__global__ __launch_bounds__(256) void k_hx(
    const unsigned short* __restrict__ x_bf, const unsigned short* __restrict__ aggx_bf,
    const unsigned short* __restrict__ aggea_bf, const float* __restrict__ degf,
    const unsigned short* __restrict__ wf1, const unsigned short* __restrict__ wf2,
    const float* __restrict__ b_self, const float* __restrict__ bsum2,
    const float* __restrict__ b_l, const float* __restrict__ b_r,
    unsigned short* __restrict__ xl_bf, unsigned short* __restrict__ xr_bf) {
    __shared__ unsigned short hs[64][264];
    int w = threadIdx.x >> 6;
    int l = threadIdx.x & 63;
    int m0 = blockIdx.x * 64;
    int quad = l >> 4, lm = l & 15;
    {
        f32x4 acc[4][4] = {};
        short8 z8 = {0, 0, 0, 0, 0, 0, 0, 0};
        #pragma unroll
        for (int kt = 0; kt < 5; ++kt) {
            short8 a[4], b[4];
            #pragma unroll
            for (int mt = 0; mt < 4; ++mt) {
                int row = m0 + mt * 16 + lm;
                if (kt < 2)
                    a[mt] = *(const short8*)(x_bf + (size_t)row * 64 + kt * 32 + quad * 8);
                else if (kt < 4)
                    a[mt] = *(const short8*)(aggx_bf + (size_t)row * 64 + (kt - 2) * 32 + quad * 8);
                else
                    a[mt] = (quad < 2)
                        ? *(const short8*)(aggea_bf + (size_t)row * 16 + quad * 8)
                        : z8;
            }
            #pragma unroll
            for (int nt = 0; nt < 4; ++nt)
                b[nt] = *(const short8*)(wf1 + (((size_t)(w * 4 + nt) * 5 + kt) * 64 + l) * 8);
            #pragma unroll
            for (int mt = 0; mt < 4; ++mt)
                #pragma unroll
                for (int nt = 0; nt < 4; ++nt)
                    acc[mt][nt] = __builtin_amdgcn_mfma_f32_16x16x32_bf16(a[mt], b[nt], acc[mt][nt], 0, 0, 0);
        }
        #pragma unroll
        for (int nt = 0; nt < 4; ++nt) {
            int col = w * 64 + nt * 16 + lm;
            float bs = b_self[col];
            float b2 = bsum2[col];
            #pragma unroll
            for (int mt = 0; mt < 4; ++mt) {
                float4 dg = *(const float4*)(degf + m0 + mt * 16 + quad * 4);
                #pragma unroll
                for (int r = 0; r < 4; ++r) {
                    float v = gelu_t(acc[mt][nt][r] + bs + (&dg.x)[r] * b2);
                    hs[mt * 16 + quad * 4 + r][col] = f2bf(v);
                }
            }
        }
    }
    __syncthreads();
    f32x4 acc2[4][4] = {};
    #pragma unroll
    for (int kt = 0; kt < 8; ++kt) {
        short8 a[4], b[4];
        #pragma unroll
        for (int mt = 0; mt < 4; ++mt)
            a[mt] = *(const short8*)(&hs[mt * 16 + lm][kt * 32 + quad * 8]);
        #pragma unroll
        for (int nt = 0; nt < 4; ++nt)
            b[nt] = *(const short8*)(wf2 + (((size_t)(w * 4 + nt) * 8 + kt) * 64 + l) * 8);
        #pragma unroll
        for (int mt = 0; mt < 4; ++mt)
            #pragma unroll
            for (int nt = 0; nt < 4; ++nt)
                acc2[mt][nt] = __builtin_amdgcn_mfma_f32_16x16x32_bf16(a[mt], b[nt], acc2[mt][nt], 0, 0, 0);
    }
    bool isl = (w < 2);
    unsigned short* outp = isl ? xl_bf : xr_bf;
    int colbase = isl ? w * 64 : (w - 2) * 64;
    const float* bias = isl ? b_l : b_r;
    #pragma unroll
    for (int nt = 0; nt < 4; ++nt) {
        int col = colbase + nt * 16 + lm;
        float bv = bias[col];
        #pragma unroll
        for (int mt = 0; mt < 4; ++mt) {
            #pragma unroll
            for (int r = 0; r < 4; ++r) {
                int row = m0 + mt * 16 + quad * 4 + r;
                outp[(size_t)row * 128 + col] = f2bf(acc2[mt][nt][r] + bv);
            }
        }
    }
}

// ---------------- edge score helper (uint4 direct, packed bf16 dot2) ---------
__device__ __forceinline__ float edge_score_q(uint4 q0, uint4 q1,
                                              unsigned pl, float xr0, float xr1,
                                              const unsigned* wp0, const unsigned* wp1,
                                              float a0, float a1) {
    float m0 = bfl(pl) + xr0;
    float m1 = bfh(pl) + xr1;
    m0 = dot2bf(q0.x, wp0[0], m0); m1 = dot2bf(q0.x, wp1[0], m1);
    m0 = dot2bf(q0.y, wp0[1], m0); m1 = dot2bf(q0.y, wp1[1], m1);
    m0 = dot2bf(q0.z, wp0[2], m0); m1 = dot2bf(q0.z, wp1[2], m1);
    m0 = dot2bf(q0.w, wp0[3], m0); m1 = dot2bf(q0.w, wp1[3], m1);
    m0 = dot2bf(q1.x, wp0[4], m0); m1 = dot2bf(q1.x, wp1[4], m1);
    m0 = dot2bf(q1.y, wp0[5], m0); m1 = dot2bf(q1.y, wp1[5], m1);
    m0 = dot2bf(q1.z, wp0[6], m0); m1 = dot2bf(q1.z, wp1[6], m1);
    m0 = dot2bf(q1.w, wp0[7], m0); m1 = dot2bf(q1.w, wp1[7], m1);
    m0 = (m0 > 0.f) ? m0 : 0.2f * m0;
    m1 = (m1 > 0.f) ? m1 : 0.2f * m1;
    float part = m0 * a0 + m1 * a1;
    #pragma unroll
    for (int off = 32; off; off >>= 1) part += __shfl_xor(part, off, 64);
    return part;
}

__device__ __forceinline__ void online_upd(float al, unsigned p, float& m_run,
                                           float& l_run, float& n0, float& n1) {
    if (al > m_run) {
        float sc = __expf(m_run - al);
        l_run *= sc; n0 *= sc; n1 *= sc;
        m_run = al;
    }
    float wgt = __expf(al - m_run);
    l_run += wgt;
    n0 += wgt * bfl(p);
    n1 += wgt * bfh(p);
}

// ---------------- Kernel D: fused per-dst GATv2 (uniform-bounds SMEM loads) --
__global__ __launch_bounds__(256) void k_gat(
    const unsigned* __restrict__ xlw, const unsigned* __restrict__ xrw,
    const unsigned short* __restrict__ ea_csr, const int* __restrict__ csr_src,
    const int* __restrict__ row_ptr, const unsigned short* __restrict__ aggea_bf,
    const unsigned* __restrict__ we2p, const float* __restrict__ att,
    const float* __restrict__ bias2, const int* __restrict__ batch,
    float* __restrict__ gsum, float* __restrict__ cnt) {
    int d = rfl(blockIdx.x * 4 + (threadIdx.x >> 6));
    int lane = threadIdx.x & 63;
    if (d >= NN) return;
    unsigned wp0[8], wp1[8];
    #pragma unroll
    for (int t = 0; t < 8; ++t) {
        uint2 wv = *(const uint2*)(we2p + t * 128 + 2 * lane);
        wp0[t] = wv.x; wp1[t] = wv.y;
    }
    float2 av = *(const float2*)(att + 2 * lane);
    float a0 = av.x, a1 = av.y;
    // wave-uniform bounds: lets the backend scalarize csr_src / ea loads
    int beg = rfl(row_ptr[d]);
    int end = rfl(row_ptr[d + 1]);
    const uint4* eap = (const uint4*)ea_csr;
    unsigned pld = xlw[(size_t)d * 64 + lane];
    unsigned prd = xrw[(size_t)d * 64 + lane];
    float xr0 = bfl(prd), xr1 = bfh(prd);
    float inv = 1.0f / fmaxf((float)(end - beg), 1.0f);
    float al_loop;
    {
        const uint4* ae = (const uint4*)(aggea_bf + (size_t)d * 16);
        uint4 q0 = ae[0], q1 = ae[1];
        float d0 = 0.f, d1 = 0.f;
        d0 = dot2bf(q0.x, wp0[0], d0); d1 = dot2bf(q0.x, wp1[0], d1);
        d0 = dot2bf(q0.y, wp0[1], d0); d1 = dot2bf(q0.y, wp1[1], d1);
        d0 = dot2bf(q0.z, wp0[2], d0); d1 = dot2bf(q0.z, wp1[2], d1);
        d0 = dot2bf(q0.w, wp0[3], d0); d1 = dot2bf(q0.w, wp1[3], d1);
        d0 = dot2bf(q1.x, wp0[4], d0); d1 = dot2bf(q1.x, wp1[4], d1);
        d0 = dot2bf(q1.y, wp0[5], d0); d1 = dot2bf(q1.y, wp1[5], d1);
        d0 = dot2bf(q1.z, wp0[6], d0); d1 = dot2bf(q1.z, wp1[6], d1);
        d0 = dot2bf(q1.w, wp0[7], d0); d1 = dot2bf(q1.w, wp1[7], d1);
        float m0 = bfl(pld) + xr0 + inv * d0;
        float m1 = bfh(pld) + xr1 + inv * d1;
        m0 = (m0 > 0.f) ? m0 : 0.2f * m0;
        m1 = (m1 > 0.f) ? m1 : 0.2f * m1;
        float part = m0 * a0 + m1 * a1;
        #pragma unroll
        for (int off = 32; off; off >>= 1) part += __shfl_xor(part, off, 64);
        al_loop = part;
    }
    float m_run = al_loop, l_run = 1.0f;
    float n0 = bfl(pld), n1 = bfh(pld);
    int i = beg;
    for (; i + 3 < end; i += 4) {
        int s0 = rfl(csr_src[i]),     s1 = rfl(csr_src[i + 1]);
        int s2 = rfl(csr_src[i + 2]), s3 = rfl(csr_src[i + 3]);
        uint4 qa0 = eap[(size_t)i * 2],       qa1 = eap[(size_t)i * 2 + 1];
        uint4 qb0 = eap[(size_t)(i + 1) * 2], qb1 = eap[(size_t)(i + 1) * 2 + 1];
        uint4 qc0 = eap[(size_t)(i + 2) * 2], qc1 = eap[(size_t)(i + 2) * 2 + 1];
        uint4 qd0 = eap[(size_t)(i + 3) * 2], qd1 = eap[(size_t)(i + 3) * 2 + 1];
        unsigned p0 = xlw[(size_t)s0 * 64 + lane];
        unsigned p1 = xlw[(size_t)s1 * 64 + lane];
        unsigned p2 = xlw[(size_t)s2 * 64 + lane];
        unsigned p3 = xlw[(size_t)s3 * 64 + lane];
        float al0 = edge_score_q(qa0, qa1, p0, xr0, xr1, wp0, wp1, a0, a1);
        float al1 = edge_score_q(qb0, qb1, p1, xr0, xr1, wp0, wp1, a0, a1);
        float al2 = edge_score_q(qc0, qc1, p2, xr0, xr1, wp0, wp1, a0, a1);
        float al3 = edge_score_q(qd0, qd1, p3, xr0, xr1, wp0, wp1, a0, a1);
        float gm = fmaxf(fmaxf(al0, al1), fmaxf(al2, al3));
        if (gm > m_run) {
            float sc = __expf(m_run - gm);
            l_run *= sc; n0 *= sc; n1 *= sc;
            m_run = gm;
        }
        float w0 = __expf(al0 - m_run);
        float w1 = __expf(al1 - m_run);
        float w2 = __expf(al2 - m_run);
        float w3 = __expf(al3 - m_run);
        l_run += (w0 + w1) + (w2 + w3);
        n0 += w0 * bfl(p0) + w1 * bfl(p1) + w2 * bfl(p2) + w3 * bfl(p3);
        n1 += w0 * bfh(p0) + w1 * bfh(p1) + w2 * bfh(p2) + w3 * bfh(p3);
    }
    for (; i < end; ++i) {
        int s = rfl(csr_src[i]);
        uint4 q0 = eap[(size_t)i * 2], q1 = eap[(size_t)i * 2 + 1];
        unsigned p = xlw[(size_t)s * 64 + lane];
        float al = edge_score_q(q0, q1, p, xr0, xr1, wp0, wp1, a0, a1);
        online_upd(al, p, m_run, l_run, n0, n1);
    }
    float rinv = 1.0f / l_run;
    float2 bv = *(const float2*)(bias2 + 2 * lane);
    float o0 = n0 * rinv + bv.x;
    float o1 = n1 * rinv + bv.y;
    int g = batch[d];
    atomAddF(&gsum[(size_t)g * 128 + 2 * lane], o0);
    atomAddF(&gsum[(size_t)g * 128 + 2 * lane + 1], o1);
    if (lane == 0) atomAddF(&cnt[g], 1.0f);
}

// ---------------- Kernel G: FFN ----------------------------------------------
__global__ __launch_bounds__(256) void k_ffn(
    const float* __restrict__ gsum, const float* __restrict__ cnt,
    const float* __restrict__ W1, const float* __restrict__ b1,
    const float* __restrict__ W2, const float* __restrict__ b2,
    float* __restrict__ y) {
    __shared__ float row[128];
    __shared__ float red[4];
    int g = blockIdx.x;
    int t = threadIdx.x;
    if (t < 128) row[t] = gsum[(size_t)g * 128 + t] / fmaxf(cnt[g], 1.0f);
    __syncthreads();
    float part = 0.f;
    #pragma unroll
    for (int jj = 0; jj < 2; ++jj) {
        int j = t + jj * 256;
        float acc = b1[j];
        for (int k = 0; k < 128; ++k) acc += row[k] * W1[k * 512 + j];
        part += gelu_t(acc) * W2[j];
    }
    #pragma unroll
    for (int off = 32; off; off >>= 1) part += __shfl_xor(part, off, 64);
    if ((t & 63) == 0) red[t >> 6] = part;
    __syncthreads();
    if (t == 0) y[g] = red[0] + red[1] + red[2] + red[3] + b2[0];
}

extern "C" void kernel_launch(void* const* d_in, const int* in_sizes, int n_in,
                              void* d_out, int out_size, void* d_ws, size_t ws_size,
                              hipStream_t stream) {
    const float* x      = (const float*)d_in[0];
    const int*   eidx   = (const int*)d_in[1];
    const float* eattr  = (const float*)d_in[2];
    const int*   batch  = (const int*)d_in[3];
    const float* W_msg  = (const float*)d_in[4];
    const float* b_msg  = (const float*)d_in[5];
    const float* W_e1   = (const float*)d_in[6];
    const float* b_e1   = (const float*)d_in[7];
    const float* W_self = (const float*)d_in[8];
    const float* b_self = (const float*)d_in[9];
    const float* W_l    = (const float*)d_in[10];
    const float* b_l    = (const float*)d_in[11];
    const float* W_r    = (const float*)d_in[12];
    const float* b_r    = (const float*)d_in[13];
    const float* W_e2   = (const float*)d_in[14];
    const float* att    = (const float*)d_in[15];
    const float* bias2  = (const float*)d_in[16];
    const float* W1     = (const float*)d_in[17];
    const float* b1     = (const float*)d_in[18];
    const float* W2     = (const float*)d_in[19];
    const float* b2     = (const float*)d_in[20];
    const int* src = eidx;
    const int* dst = eidx + NE;

    char* wsb = (char*)d_ws;
    size_t o = 0;
    int*   hist   = (int*)(wsb + o);   o += (size_t)8 * NN * 4;   // 8 partitions
    float* gsum   = (float*)(wsb + o); o += (size_t)NG * 128 * 4;
    float* cnt    = (float*)(wsb + o); o += 4096;
    size_t zero_bytes = o;
    int*   dsum    = (int*)(wsb + o);  o += (size_t)40960 * 4;
    int*   row_ptr = (int*)(wsb + o);  o += (size_t)40964 * 4;
    int*   off     = (int*)(wsb + o);  o += (size_t)8 * NN * 4;
    int*   rank    = (int*)(wsb + o);  o += (size_t)NE * 4;
    int*   csr_src = (int*)(wsb + o);  o += (size_t)NE * 4;
    unsigned short* ea_csr = (unsigned short*)(wsb + o); o += (size_t)NE * 16 * 2;
    unsigned short* aggx_bf  = (unsigned short*)(wsb + o); o += (size_t)NN * 64 * 2;
    unsigned short* aggea_bf = (unsigned short*)(wsb + o); o += (size_t)NN * 16 * 2;
    float* degf    = (float*)(wsb + o); o += (size_t)NN * 4;
    unsigned short* x_bf  = (unsigned short*)(wsb + o); o += (size_t)NN * 64 * 2;
    unsigned short* xl_bf = (unsigned short*)(wsb + o); o += (size_t)NN * 128 * 2;
    unsigned short* xr_bf = (unsigned short*)(wsb + o); o += (size_t)NN * 128 * 2;
    unsigned short* wf1   = (unsigned short*)(wsb + o); o += (size_t)5120 * 8 * 2;
    unsigned short* wf2   = (unsigned short*)(wsb + o); o += (size_t)8192 * 8 * 2;
    unsigned* we2p = (unsigned*)(wsb + o); o += (size_t)1024 * 4;
    float* bsum2  = (float*)(wsb + o); o += 1024;

    hipMemsetAsync(d_ws, 0, zero_bytes, stream);
    hipLaunchKernelGGL(k_pre, dim3(2500), dim3(256), 0, stream,
                       x, dst, W_self, W_msg, W_e1, b_msg, b_e1, W_l, W_r, W_e2,
                       x_bf, hist, rank, wf1, wf2, we2p, bsum2);
    hipLaunchKernelGGL(k_dsum, dim3(160), dim3(256), 0, stream, hist, dsum);
    hipLaunchKernelGGL(k_scan, dim3(1), dim3(1024), 0, stream, dsum, row_ptr);
    hipLaunchKernelGGL(k_off, dim3((NN + 255) / 256), dim3(256), 0, stream,
                       hist, row_ptr, off);
    hipLaunchKernelGGL(k_scatter, dim3(2500), dim3(256), 0, stream,
                       src, dst, rank, off, eattr, csr_src, ea_csr);
    hipLaunchKernelGGL(k_agg, dim3((NN + 3) / 4), dim3(256), 0, stream,
                       x_bf, ea_csr, csr_src, row_ptr, aggx_bf, aggea_bf, degf);
    hipLaunchKernelGGL(k_hx, dim3(625), dim3(256), 0, stream,
                       x_bf, aggx_bf, aggea_bf, degf, wf1, wf2,
                       b_self, bsum2, b_l, b_r, xl_bf, xr_bf);
    hipLaunchKernelGGL(k_gat, dim3((NN + 3) / 4), dim3(256), 0, stream,
                       (const unsigned*)xl_bf, (const unsigned*)xr_bf, ea_csr,
                       csr_src, row_ptr, aggea_bf, we2p, att, bias2,
                       batch, gsum, cnt);
    hipLaunchKernelGGL(k_ffn, dim3(NG), dim3(256), 0, stream,
                       gsum, cnt, W1, b1, W2, b2, (float*)d_out);
}

// Round 15
// 365.472 us; speedup vs baseline: 1.0039x; 1.0039x over previous
//
#include <hip/hip_runtime.h>
#include <hip/hip_bf16.h>

#define NN 40000
#define NE 640000
#define NG 1000

typedef __attribute__((ext_vector_type(8))) short short8;
typedef __attribute__((ext_vector_type(4))) float f32x4;
typedef __attribute__((ext_vector_type(2))) __bf16 bf16x2v;

__device__ __forceinline__ float gelu_t(float x) {
    float u = 0.7978845608028654f * (x + 0.044715f * x * x * x);
    return 0.5f * x * (1.0f + tanhf(u));
}
__device__ __forceinline__ void atomAddF(float* p, float v) {
    unsafeAtomicAdd(p, v);
}
__device__ __forceinline__ int rfl(int v) { return __builtin_amdgcn_readfirstlane(v); }
__device__ __forceinline__ unsigned short f2bf(float f) {
    unsigned u = __float_as_uint(f);
    unsigned r = (u + 0x7fffu + ((u >> 16) & 1u)) >> 16;
    return (unsigned short)r;
}
__device__ __forceinline__ unsigned pk_bf(float lo, float hi) {
    __hip_bfloat162 v = __float22bfloat162_rn(make_float2(lo, hi));
    unsigned r;
    __builtin_memcpy(&r, &v, 4);
    return r;
}
__device__ __forceinline__ float bfl(unsigned p) { return __uint_as_float(p << 16); }
__device__ __forceinline__ float bfh(unsigned p) { return __uint_as_float(p & 0xffff0000u); }

__device__ __forceinline__ float dot2bf(unsigned a, unsigned b, float c) {
#if __has_builtin(__builtin_amdgcn_fdot2_f32_bf16)
    bf16x2v av, bv;
    __builtin_memcpy(&av, &a, 4);
    __builtin_memcpy(&bv, &b, 4);
    return __builtin_amdgcn_fdot2_f32_bf16(av, bv, c, false);
#else
    return c + bfl(a) * bfl(b) + bfh(a) * bfh(b);
#endif
}

// ---------------- Kernel P: x->bf16 + 8-way partitioned histogram + packs ----
__global__ __launch_bounds__(256) void k_pre(
    const float* __restrict__ x, const int* __restrict__ dst,
    const float* __restrict__ W_self, const float* __restrict__ W_msg,
    const float* __restrict__ W_e1, const float* __restrict__ b_msg,
    const float* __restrict__ b_e1,
    const float* __restrict__ W_l, const float* __restrict__ W_r,
    const float* __restrict__ W_e2,
    unsigned short* __restrict__ x_bf, int* __restrict__ hist,
    int* __restrict__ rank,
    unsigned short* __restrict__ wf1, unsigned short* __restrict__ wf2,
    unsigned* __restrict__ we2p, float* __restrict__ bsum2) {
    int t = blockIdx.x * 256 + threadIdx.x;
    float4 v = ((const float4*)x)[t];
    ((uint2*)x_bf)[t] = make_uint2(pk_bf(v.x, v.y), pk_bf(v.z, v.w));
    int part = t / 80000;           // 8 edge-range partitions
    rank[t] = atomicAdd(&hist[part * NN + dst[t]], 1);
    if (t < 256) bsum2[t] = b_msg[t] + b_e1[t];
    if (t < 5120) {
        int l = t & 63;
        int kt = (t >> 6) % 5;
        int gnt = t / 320;
        int n = gnt * 16 + (l & 15);
        int k0 = kt * 32 + (l >> 4) * 8;
        unsigned short vv[8];
        #pragma unroll
        for (int j = 0; j < 8; ++j) {
            int k = k0 + j;
            float wv;
            if (k < 64)       wv = W_self[(size_t)k * 256 + n];
            else if (k < 128) wv = W_msg[(size_t)(k - 64) * 256 + n];
            else if (k < 144) wv = W_e1[(size_t)(k - 128) * 256 + n];
            else              wv = 0.f;
            vv[j] = f2bf(wv);
        }
        uint4 pack;
        pack.x = (unsigned)vv[0] | ((unsigned)vv[1] << 16);
        pack.y = (unsigned)vv[2] | ((unsigned)vv[3] << 16);
        pack.z = (unsigned)vv[4] | ((unsigned)vv[5] << 16);
        pack.w = (unsigned)vv[6] | ((unsigned)vv[7] << 16);
        ((uint4*)wf1)[t] = pack;
    }
    if (t >= 5120 && t < 13312) {
        int t2 = t - 5120;
        int l = t2 & 63;
        int kt = (t2 >> 6) & 7;
        int gnt = t2 >> 9;
        int n = gnt * 16 + (l & 15);
        int k0 = kt * 32 + (l >> 4) * 8;
        const float* W = (n < 128) ? W_l : W_r;
        int nn = n & 127;
        float w[8];
        #pragma unroll
        for (int j = 0; j < 8; ++j) w[j] = W[(size_t)(k0 + j) * 128 + nn];
        uint4 pack;
        pack.x = pk_bf(w[0], w[1]);
        pack.y = pk_bf(w[2], w[3]);
        pack.z = pk_bf(w[4], w[5]);
        pack.w = pk_bf(w[6], w[7]);
        ((uint4*)wf2)[t2] = pack;
    }
    if (t >= 13312 && t < 14336) {
        int t3 = t - 13312;
        int tt = t3 >> 7;
        int c = t3 & 127;
        we2p[t3] = pk_bf(W_e2[(size_t)(2 * tt) * 128 + c],
                         W_e2[(size_t)(2 * tt + 1) * 128 + c]);
    }
}

// ---------------- CSR build: parallel degree sum (padded to 40960) -----------
__global__ __launch_bounds__(256) void k_dsum(const int* __restrict__ hist,
                                              int* __restrict__ dsum) {
    int idx = blockIdx.x * 256 + threadIdx.x;
    if (idx >= 40960) return;
    int s = 0;
    if (idx < NN) {
        #pragma unroll
        for (int p = 0; p < 8; ++p) s += hist[p * NN + idx];
    }
    dsum[idx] = s;
}

// ---------------- CSR build: single-block vectorized exclusive scan ----------
__global__ __launch_bounds__(1024) void k_scan(const int* __restrict__ dsum,
                                               int* __restrict__ row_ptr) {
    __shared__ int ssum[1024];
    int t = threadIdx.x;
    int base = t * 40;             // 1024*40 = 40960 exactly
    const int4* dv = (const int4*)(dsum + base);
    int local[40];
    int s = 0;
    #pragma unroll
    for (int j = 0; j < 10; ++j) {
        int4 v = dv[j];
        local[j * 4 + 0] = s; s += v.x;
        local[j * 4 + 1] = s; s += v.y;
        local[j * 4 + 2] = s; s += v.z;
        local[j * 4 + 3] = s; s += v.w;
    }
    ssum[t] = s;
    __syncthreads();
    for (int o = 1; o < 1024; o <<= 1) {
        int tmp = (t >= o) ? ssum[t - o] : 0;
        __syncthreads();
        ssum[t] += tmp;
        __syncthreads();
    }
    int prefix = (t > 0) ? ssum[t - 1] : 0;
    int4* rv = (int4*)(row_ptr + base);
    #pragma unroll
    for (int j = 0; j < 10; ++j) {
        int4 o4;
        o4.x = prefix + local[j * 4 + 0];
        o4.y = prefix + local[j * 4 + 1];
        o4.z = prefix + local[j * 4 + 2];
        o4.w = prefix + local[j * 4 + 3];
        rv[j] = o4;
    }
}

// ---------------- CSR build: per-partition offsets (parallel) ----------------
__global__ __launch_bounds__(256) void k_off(const int* __restrict__ hist,
                                             const int* __restrict__ row_ptr,
                                             int* __restrict__ off) {
    int idx = blockIdx.x * 256 + threadIdx.x;
    if (idx >= NN) return;
    int acc = row_ptr[idx];
    #pragma unroll
    for (int p = 0; p < 8; ++p) {
        off[p * NN + idx] = acc;
        acc += hist[p * NN + idx];
    }
}

// ---------------- CSR build: atomic-free scatter -----------------------------
__global__ __launch_bounds__(256) void k_scatter(const int* __restrict__ src,
                                                 const int* __restrict__ dst,
                                                 const int* __restrict__ rank,
                                                 const int* __restrict__ off,
                                                 const float* __restrict__ eattr,
                                                 int* __restrict__ csr_src,
                                                 unsigned short* __restrict__ ea_csr) {
    int e = blockIdx.x * 256 + threadIdx.x;
    if (e >= NE) return;
    int d = dst[e];
    int p = e / 80000;
    int pos = off[p * NN + d] + rank[e];
    csr_src[pos] = src[e];
    const float4* ep = (const float4*)(eattr + (size_t)e * 16);
    float4 a = ep[0], b = ep[1], c = ep[2], dd = ep[3];
    uint4 q0, q1;
    q0.x = pk_bf(a.x, a.y); q0.y = pk_bf(a.z, a.w);
    q0.z = pk_bf(b.x, b.y); q0.w = pk_bf(b.z, b.w);
    q1.x = pk_bf(c.x, c.y); q1.y = pk_bf(c.z, c.w);
    q1.z = pk_bf(dd.x, dd.y); q1.w = pk_bf(dd.z, dd.w);
    uint4* out = (uint4*)ea_csr;
    out[(size_t)pos * 2]     = q0;
    out[(size_t)pos * 2 + 1] = q1;
}

// ---------------- Kernel A: per-dst gather aggregation (r13 quarter-wave) ----
__global__ __launch_bounds__(256) void k_agg(
    const unsigned short* __restrict__ x_bf, const unsigned short* __restrict__ ea_csr,
    const int* __restrict__ csr_src, const int* __restrict__ row_ptr,
    unsigned short* __restrict__ aggx_bf, unsigned short* __restrict__ aggea_bf,
    float* __restrict__ degf) {
    int d = rfl(blockIdx.x * 4 + (threadIdx.x >> 6));
    int lane = threadIdx.x & 63;
    if (d >= NN) return;
    int beg = row_ptr[d], end = row_ptr[d + 1];
    const uint2* xw2 = (const uint2*)x_bf;     // row = 16 uint2
    const unsigned* eaw = (const unsigned*)ea_csr;
    int q = lane >> 4;        // quarter 0..3
    int ql = lane & 15;       // lane-in-quarter: cols [4*ql, 4*ql+4)
    float s0a = 0.f, s1a = 0.f, s2a = 0.f, s3a = 0.f;
    float s0b = 0.f, s1b = 0.f, s2b = 0.f, s3b = 0.f;
    int i = beg;
    for (; i + 7 < end; i += 8) {
        int sA = csr_src[i + q];
        int sB = csr_src[i + 4 + q];
        uint2 wA = xw2[(size_t)sA * 16 + ql];
        uint2 wB = xw2[(size_t)sB * 16 + ql];
        s0a += bfl(wA.x); s1a += bfh(wA.x); s2a += bfl(wA.y); s3a += bfh(wA.y);
        s0b += bfl(wB.x); s1b += bfh(wB.x); s2b += bfl(wB.y); s3b += bfh(wB.y);
    }
    for (; i + q < end; i += 4) {
        int s = csr_src[i + q];
        uint2 w = xw2[(size_t)s * 16 + ql];
        s0a += bfl(w.x); s1a += bfh(w.x); s2a += bfl(w.y); s3a += bfh(w.y);
    }
    float sx0 = s0a + s0b, sx1 = s1a + s1b, sx2 = s2a + s2b, sx3 = s3a + s3b;
    sx0 += __shfl_xor(sx0, 16, 64); sx0 += __shfl_xor(sx0, 32, 64);
    sx1 += __shfl_xor(sx1, 16, 64); sx1 += __shfl_xor(sx1, 32, 64);
    sx2 += __shfl_xor(sx2, 16, 64); sx2 += __shfl_xor(sx2, 32, 64);
    sx3 += __shfl_xor(sx3, 16, 64); sx3 += __shfl_xor(sx3, 32, 64);
    // --- ea: flat sequential sum; uint p covers cols (2*(p&7), +1)
    float se0 = 0.f, se1 = 0.f, se0b = 0.f, se1b = 0.f;
    int p = beg * 8 + lane;
    int pend = end * 8;
    for (; p + 64 < pend; p += 128) {
        unsigned w = eaw[p];
        unsigned w2 = eaw[p + 64];
        se0 += bfl(w); se1 += bfh(w);
        se0b += bfl(w2); se1b += bfh(w2);
    }
    if (p < pend) {
        unsigned w = eaw[p];
        se0 += bfl(w); se1 += bfh(w);
    }
    se0 += se0b; se1 += se1b;
    #pragma unroll
    for (int off = 8; off < 64; off <<= 1) {
        se0 += __shfl_xor(se0, off, 64);
        se1 += __shfl_xor(se1, off, 64);
    }
    if (q == 0)
        ((uint2*)aggx_bf)[(size_t)d * 16 + ql] =
            make_uint2(pk_bf(sx0, sx1), pk_bf(sx2, sx3));
    if (lane < 8) ((unsigned*)aggea_bf)[(size_t)d * 8 + lane] = pk_bf(se0, se1);
    if (lane == 0) degf[d] = (float)(end - beg);
}

// ---------------- Kernel HX: fused h-GEMM + xl/xr-GEMM (MFMA, LDS-staged) ----
__global__ __launch_bounds__(256) void k_hx(
    const unsigned short* __restrict__ x_bf, const unsigned short* __restrict__ aggx_bf,
    const unsigned short* __restrict__ aggea_bf, const float* __restrict__ degf,
    const unsigned short* __restrict__ wf1, const unsigned short* __restrict__ wf2,
    const float* __restrict__ b_self, const float* __restrict__ bsum2,
    const float* __restrict__ b_l, const float* __restrict__ b_r,
    unsigned short* __restrict__ xl_bf, unsigned short* __restrict__ xr_bf) {
    __shared__ unsigned short hs[64][264];
    int w = threadIdx.x >> 6;
    int l = threadIdx.x & 63;
    int m0 = blockIdx.x * 64;
    int quad = l >> 4, lm = l & 15;
    {
        f32x4 acc[4][4] = {};
        short8 z8 = {0, 0, 0, 0, 0, 0, 0, 0};
        #pragma unroll
        for (int kt = 0; kt < 5; ++kt) {
            short8 a[4], b[4];
            #pragma unroll
            for (int mt = 0; mt < 4; ++mt) {
                int row = m0 + mt * 16 + lm;
                if (kt < 2)
                    a[mt] = *(const short8*)(x_bf + (size_t)row * 64 + kt * 32 + quad * 8);
                else if (kt < 4)
                    a[mt] = *(const short8*)(aggx_bf + (size_t)row * 64 + (kt - 2) * 32 + quad * 8);
                else
                    a[mt] = (quad < 2)
                        ? *(const short8*)(aggea_bf + (size_t)row * 16 + quad * 8)
                        : z8;
            }
            #pragma unroll
            for (int nt = 0; nt < 4; ++nt)
                b[nt] = *(const short8*)(wf1 + (((size_t)(w * 4 + nt) * 5 + kt) * 64 + l) * 8);
            #pragma unroll
            for (int mt = 0; mt < 4; ++mt)
                #pragma unroll
                for (int nt = 0; nt < 4; ++nt)
                    acc[mt][nt] = __builtin_amdgcn_mfma_f32_16x16x32_bf16(a[mt], b[nt], acc[mt][nt], 0, 0, 0);
        }
        #pragma unroll
        for (int nt = 0; nt < 4; ++nt) {
            int col = w * 64 + nt * 16 + lm;
            float bs = b_self[col];
            float b2 = bsum2[col];
            #pragma unroll
            for (int mt = 0; mt < 4; ++mt) {
                float4 dg = *(const float4*)(degf + m0 + mt * 16 + quad * 4);
                #pragma unroll
                for (int r = 0; r < 4; ++r) {
                    float v = gelu_t(acc[mt][nt][r] + bs + (&dg.x)[r] * b2);
                    hs[mt * 16 + quad * 4 + r][col] = f2bf(v);
                }
            }
        }
    }
    __syncthreads();
    f32x4 acc2[4][4] = {};
    #pragma unroll
    for (int kt = 0; kt < 8; ++kt) {
        short8 a[4], b[4];
        #pragma unroll
        for (int mt = 0; mt < 4; ++mt)
            a[mt] = *(const short8*)(&hs[mt * 16 + lm][kt * 32 + quad * 8]);
        #pragma unroll
        for (int nt = 0; nt < 4; ++nt)
            b[nt] = *(const short8*)(wf2 + (((size_t)(w * 4 + nt) * 8 + kt) * 64 + l) * 8);
        #pragma unroll
        for (int mt = 0; mt < 4; ++mt)
            #pragma unroll
            for (int nt = 0; nt < 4; ++nt)
                acc2[mt][nt] = __builtin_amdgcn_mfma_f32_16x16x32_bf16(a[mt], b[nt], acc2[mt][nt], 0, 0, 0);
    }
    bool isl = (w < 2);
    unsigned short* outp = isl ? xl_bf : xr_bf;
    int colbase = isl ? w * 64 : (w - 2) * 64;
    const float* bias = isl ? b_l : b_r;
    #pragma unroll
    for (int nt = 0; nt < 4; ++nt) {
        int col = colbase + nt * 16 + lm;
        float bv = bias[col];
        #pragma unroll
        for (int mt = 0; mt < 4; ++mt) {
            #pragma unroll
            for (int r = 0; r < 4; ++r) {
                int row = m0 + mt * 16 + quad * 4 + r;
                outp[(size_t)row * 128 + col] = f2bf(acc2[mt][nt][r] + bv);
            }
        }
    }
}

// ---------------- edge score helper (uint4 direct, packed bf16 dot2) ---------
__device__ __forceinline__ float edge_score_q(uint4 q0, uint4 q1,
                                              unsigned pl, float xr0, float xr1,
                                              const unsigned* wp0, const unsigned* wp1,
                                              float a0, float a1) {
    float m0 = bfl(pl) + xr0;
    float m1 = bfh(pl) + xr1;
    m0 = dot2bf(q0.x, wp0[0], m0); m1 = dot2bf(q0.x, wp1[0], m1);
    m0 = dot2bf(q0.y, wp0[1], m0); m1 = dot2bf(q0.y, wp1[1], m1);
    m0 = dot2bf(q0.z, wp0[2], m0); m1 = dot2bf(q0.z, wp1[2], m1);
    m0 = dot2bf(q0.w, wp0[3], m0); m1 = dot2bf(q0.w, wp1[3], m1);
    m0 = dot2bf(q1.x, wp0[4], m0); m1 = dot2bf(q1.x, wp1[4], m1);
    m0 = dot2bf(q1.y, wp0[5], m0); m1 = dot2bf(q1.y, wp1[5], m1);
    m0 = dot2bf(q1.z, wp0[6], m0); m1 = dot2bf(q1.z, wp1[6], m1);
    m0 = dot2bf(q1.w, wp0[7], m0); m1 = dot2bf(q1.w, wp1[7], m1);
    m0 = (m0 > 0.f) ? m0 : 0.2f * m0;
    m1 = (m1 > 0.f) ? m1 : 0.2f * m1;
    float part = m0 * a0 + m1 * a1;
    #pragma unroll
    for (int off = 32; off; off >>= 1) part += __shfl_xor(part, off, 64);
    return part;
}

__device__ __forceinline__ void online_upd(float al, unsigned p, float& m_run,
                                           float& l_run, float& n0, float& n1) {
    if (al > m_run) {
        float sc = __expf(m_run - al);
        l_run *= sc; n0 *= sc; n1 *= sc;
        m_run = al;
    }
    float wgt = __expf(al - m_run);
    l_run += wgt;
    n0 += wgt * bfl(p);
    n1 += wgt * bfh(p);
}

// ---------------- Kernel D: fused per-dst GATv2 (8-edge groups) --------------
__global__ __launch_bounds__(256) void k_gat(
    const unsigned* __restrict__ xlw, const unsigned* __restrict__ xrw,
    const unsigned short* __restrict__ ea_csr, const int* __restrict__ csr_src,
    const int* __restrict__ row_ptr, const unsigned short* __restrict__ aggea_bf,
    const unsigned* __restrict__ we2p, const float* __restrict__ att,
    const float* __restrict__ bias2, const int* __restrict__ batch,
    float* __restrict__ gsum, float* __restrict__ cnt) {
    int d = rfl(blockIdx.x * 4 + (threadIdx.x >> 6));
    int lane = threadIdx.x & 63;
    if (d >= NN) return;
    unsigned wp0[8], wp1[8];
    #pragma unroll
    for (int t = 0; t < 8; ++t) {
        uint2 wv = *(const uint2*)(we2p + t * 128 + 2 * lane);
        wp0[t] = wv.x; wp1[t] = wv.y;
    }
    float2 av = *(const float2*)(att + 2 * lane);
    float a0 = av.x, a1 = av.y;
    int beg = row_ptr[d], end = row_ptr[d + 1];
    const uint4* eap = (const uint4*)ea_csr;
    unsigned pld = xlw[(size_t)d * 64 + lane];
    unsigned prd = xrw[(size_t)d * 64 + lane];
    float xr0 = bfl(prd), xr1 = bfh(prd);
    float inv = 1.0f / fmaxf((float)(end - beg), 1.0f);
    float al_loop;
    {
        const uint4* ae = (const uint4*)(aggea_bf + (size_t)d * 16);
        uint4 q0 = ae[0], q1 = ae[1];
        float d0 = 0.f, d1 = 0.f;
        d0 = dot2bf(q0.x, wp0[0], d0); d1 = dot2bf(q0.x, wp1[0], d1);
        d0 = dot2bf(q0.y, wp0[1], d0); d1 = dot2bf(q0.y, wp1[1], d1);
        d0 = dot2bf(q0.z, wp0[2], d0); d1 = dot2bf(q0.z, wp1[2], d1);
        d0 = dot2bf(q0.w, wp0[3], d0); d1 = dot2bf(q0.w, wp1[3], d1);
        d0 = dot2bf(q1.x, wp0[4], d0); d1 = dot2bf(q1.x, wp1[4], d1);
        d0 = dot2bf(q1.y, wp0[5], d0); d1 = dot2bf(q1.y, wp1[5], d1);
        d0 = dot2bf(q1.z, wp0[6], d0); d1 = dot2bf(q1.z, wp1[6], d1);
        d0 = dot2bf(q1.w, wp0[7], d0); d1 = dot2bf(q1.w, wp1[7], d1);
        float m0 = bfl(pld) + xr0 + inv * d0;
        float m1 = bfh(pld) + xr1 + inv * d1;
        m0 = (m0 > 0.f) ? m0 : 0.2f * m0;
        m1 = (m1 > 0.f) ? m1 : 0.2f * m1;
        float part = m0 * a0 + m1 * a1;
        #pragma unroll
        for (int off = 32; off; off >>= 1) part += __shfl_xor(part, off, 64);
        al_loop = part;
    }
    float m_run = al_loop, l_run = 1.0f;
    float n0 = bfl(pld), n1 = bfh(pld);
    int i = beg;
    // 8-edge groups: deep MLP on the xl gathers
    for (; i + 7 < end; i += 8) {
        int sx[8];
        #pragma unroll
        for (int k = 0; k < 8; ++k) sx[k] = rfl(csr_src[i + k]);
        unsigned pp[8];
        #pragma unroll
        for (int k = 0; k < 8; ++k) pp[k] = xlw[(size_t)sx[k] * 64 + lane];
        uint4 qq[16];
        #pragma unroll
        for (int k = 0; k < 8; ++k) {
            qq[2 * k]     = eap[(size_t)(i + k) * 2];
            qq[2 * k + 1] = eap[(size_t)(i + k) * 2 + 1];
        }
        float al[8];
        #pragma unroll
        for (int k = 0; k < 8; ++k)
            al[k] = edge_score_q(qq[2 * k], qq[2 * k + 1], pp[k], xr0, xr1, wp0, wp1, a0, a1);
        float gm = fmaxf(fmaxf(fmaxf(al[0], al[1]), fmaxf(al[2], al[3])),
                         fmaxf(fmaxf(al[4], al[5]), fmaxf(al[6], al[7])));
        if (gm > m_run) {
            float sc = __expf(m_run - gm);
            l_run *= sc; n0 *= sc; n1 *= sc;
            m_run = gm;
        }
        float wsum = 0.f;
        #pragma unroll
        for (int k = 0; k < 8; ++k) {
            float wk = __expf(al[k] - m_run);
            wsum += wk;
            n0 += wk * bfl(pp[k]);
            n1 += wk * bfh(pp[k]);
        }
        l_run += wsum;
    }
    // 4-edge groups
    for (; i + 3 < end; i += 4) {
        int s0 = rfl(csr_src[i]),     s1 = rfl(csr_src[i + 1]);
        int s2 = rfl(csr_src[i + 2]), s3 = rfl(csr_src[i + 3]);
        uint4 qa0 = eap[(size_t)i * 2],       qa1 = eap[(size_t)i * 2 + 1];
        uint4 qb0 = eap[(size_t)(i + 1) * 2], qb1 = eap[(size_t)(i + 1) * 2 + 1];
        uint4 qc0 = eap[(size_t)(i + 2) * 2], qc1 = eap[(size_t)(i + 2) * 2 + 1];
        uint4 qd0 = eap[(size_t)(i + 3) * 2], qd1 = eap[(size_t)(i + 3) * 2 + 1];
        unsigned p0 = xlw[(size_t)s0 * 64 + lane];
        unsigned p1 = xlw[(size_t)s1 * 64 + lane];
        unsigned p2 = xlw[(size_t)s2 * 64 + lane];
        unsigned p3 = xlw[(size_t)s3 * 64 + lane];
        float al0 = edge_score_q(qa0, qa1, p0, xr0, xr1, wp0, wp1, a0, a1);
        float al1 = edge_score_q(qb0, qb1, p1, xr0, xr1, wp0, wp1, a0, a1);
        float al2 = edge_score_q(qc0, qc1, p2, xr0, xr1, wp0, wp1, a0, a1);
        float al3 = edge_score_q(qd0, qd1, p3, xr0, xr1, wp0, wp1, a0, a1);
        float gm = fmaxf(fmaxf(al0, al1), fmaxf(al2, al3));
        if (gm > m_run) {
            float sc = __expf(m_run - gm);
            l_run *= sc; n0 *= sc; n1 *= sc;
            m_run = gm;
        }
        float w0 = __expf(al0 - m_run);
        float w1 = __expf(al1 - m_run);
        float w2 = __expf(al2 - m_run);
        float w3 = __expf(al3 - m_run);
        l_run += (w0 + w1) + (w2 + w3);
        n0 += w0 * bfl(p0) + w1 * bfl(p1) + w2 * bfl(p2) + w3 * bfl(p3);
        n1 += w0 * bfh(p0) + w1 * bfh(p1) + w2 * bfh(p2) + w3 * bfh(p3);
    }
    for (; i < end; ++i) {
        int s = rfl(csr_src[i]);
        uint4 q0 = eap[(size_t)i * 2], q1 = eap[(size_t)i * 2 + 1];
        unsigned p = xlw[(size_t)s * 64 + lane];
        float al = edge_score_q(q0, q1, p, xr0, xr1, wp0, wp1, a0, a1);
        online_upd(al, p, m_run, l_run, n0, n1);
    }
    float rinv = 1.0f / l_run;
    float2 bv = *(const float2*)(bias2 + 2 * lane);
    float o0 = n0 * rinv + bv.x;
    float o1 = n1 * rinv + bv.y;
    int g = batch[d];
    atomAddF(&gsum[(size_t)g * 128 + 2 * lane], o0);
    atomAddF(&gsum[(size_t)g * 128 + 2 * lane + 1], o1);
    if (lane == 0) atomAddF(&cnt[g], 1.0f);
}

// ---------------- Kernel G: FFN ----------------------------------------------
__global__ __launch_bounds__(256) void k_ffn(
    const float* __restrict__ gsum, const float* __restrict__ cnt,
    const float* __restrict__ W1, const float* __restrict__ b1,
    const float* __restrict__ W2, const float* __restrict__ b2,
    float* __restrict__ y) {
    __shared__ float row[128];
    __shared__ float red[4];
    int g = blockIdx.x;
    int t = threadIdx.x;
    if (t < 128) row[t] = gsum[(size_t)g * 128 + t] / fmaxf(cnt[g], 1.0f);
    __syncthreads();
    float part = 0.f;
    #pragma unroll
    for (int jj = 0; jj < 2; ++jj) {
        int j = t + jj * 256;
        float acc = b1[j];
        for (int k = 0; k < 128; ++k) acc += row[k] * W1[k * 512 + j];
        part += gelu_t(acc) * W2[j];
    }
    #pragma unroll
    for (int off = 32; off; off >>= 1) part += __shfl_xor(part, off, 64);
    if ((t & 63) == 0) red[t >> 6] = part;
    __syncthreads();
    if (t == 0) y[g] = red[0] + red[1] + red[2] + red[3] + b2[0];
}

extern "C" void kernel_launch(void* const* d_in, const int* in_sizes, int n_in,
                              void* d_out, int out_size, void* d_ws, size_t ws_size,
                              hipStream_t stream) {
    const float* x      = (const float*)d_in[0];
    const int*   eidx   = (const int*)d_in[1];
    const float* eattr  = (const float*)d_in[2];
    const int*   batch  = (const int*)d_in[3];
    const float* W_msg  = (const float*)d_in[4];
    const float* b_msg  = (const float*)d_in[5];
    const float* W_e1   = (const float*)d_in[6];
    const float* b_e1   = (const float*)d_in[7];
    const float* W_self = (const float*)d_in[8];
    const float* b_self = (const float*)d_in[9];
    const float* W_l    = (const float*)d_in[10];
    const float* b_l    = (const float*)d_in[11];
    const float* W_r    = (const float*)d_in[12];
    const float* b_r    = (const float*)d_in[13];
    const float* W_e2   = (const float*)d_in[14];
    const float* att    = (const float*)d_in[15];
    const float* bias2  = (const float*)d_in[16];
    const float* W1     = (const float*)d_in[17];
    const float* b1     = (const float*)d_in[18];
    const float* W2     = (const float*)d_in[19];
    const float* b2     = (const float*)d_in[20];
    const int* src = eidx;
    const int* dst = eidx + NE;

    char* wsb = (char*)d_ws;
    size_t o = 0;
    int*   hist   = (int*)(wsb + o);   o += (size_t)8 * NN * 4;   // 8 partitions
    float* gsum   = (float*)(wsb + o); o += (size_t)NG * 128 * 4;
    float* cnt    = (float*)(wsb + o); o += 4096;
    size_t zero_bytes = o;
    int*   dsum    = (int*)(wsb + o);  o += (size_t)40960 * 4;
    int*   row_ptr = (int*)(wsb + o);  o += (size_t)40964 * 4;
    int*   off     = (int*)(wsb + o);  o += (size_t)8 * NN * 4;
    int*   rank    = (int*)(wsb + o);  o += (size_t)NE * 4;
    int*   csr_src = (int*)(wsb + o);  o += (size_t)NE * 4;
    unsigned short* ea_csr = (unsigned short*)(wsb + o); o += (size_t)NE * 16 * 2;
    unsigned short* aggx_bf  = (unsigned short*)(wsb + o); o += (size_t)NN * 64 * 2;
    unsigned short* aggea_bf = (unsigned short*)(wsb + o); o += (size_t)NN * 16 * 2;
    float* degf    = (float*)(wsb + o); o += (size_t)NN * 4;
    unsigned short* x_bf  = (unsigned short*)(wsb + o); o += (size_t)NN * 64 * 2;
    unsigned short* xl_bf = (unsigned short*)(wsb + o); o += (size_t)NN * 128 * 2;
    unsigned short* xr_bf = (unsigned short*)(wsb + o); o += (size_t)NN * 128 * 2;
    unsigned short* wf1   = (unsigned short*)(wsb + o); o += (size_t)5120 * 8 * 2;
    unsigned short* wf2   = (unsigned short*)(wsb + o); o += (size_t)8192 * 8 * 2;
    unsigned* we2p = (unsigned*)(wsb + o); o += (size_t)1024 * 4;
    float* bsum2  = (float*)(wsb + o); o += 1024;

    hipMemsetAsync(d_ws, 0, zero_bytes, stream);
    hipLaunchKernelGGL(k_pre, dim3(2500), dim3(256), 0, stream,
                       x, dst, W_self, W_msg, W_e1, b_msg, b_e1, W_l, W_r, W_e2,
                       x_bf, hist, rank, wf1, wf2, we2p, bsum2);
    hipLaunchKernelGGL(k_dsum, dim3(160), dim3(256), 0, stream, hist, dsum);
    hipLaunchKernelGGL(k_scan, dim3(1), dim3(1024), 0, stream, dsum, row_ptr);
    hipLaunchKernelGGL(k_off, dim3((NN + 255) / 256), dim3(256), 0, stream,
                       hist, row_ptr, off);
    hipLaunchKernelGGL(k_scatter, dim3(2500), dim3(256), 0, stream,
                       src, dst, rank, off, eattr, csr_src, ea_csr);
    hipLaunchKernelGGL(k_agg, dim3((NN + 3) / 4), dim3(256), 0, stream,
                       x_bf, ea_csr, csr_src, row_ptr, aggx_bf, aggea_bf, degf);
    hipLaunchKernelGGL(k_hx, dim3(625), dim3(256), 0, stream,
                       x_bf, aggx_bf, aggea_bf, degf, wf1, wf2,
                       b_self, bsum2, b_l, b_r, xl_bf, xr_bf);
    hipLaunchKernelGGL(k_gat, dim3((NN + 3) / 4), dim3(256), 0, stream,
                       (const unsigned*)xl_bf, (const unsigned*)xr_bf, ea_csr,
                       csr_src, row_ptr, aggea_bf, we2p, att, bias2,
                       batch, gsum, cnt);
    hipLaunchKernelGGL(k_ffn, dim3(NG), dim3(256), 0, stream,
                       gsum, cnt, W1, b1, W2, b2, (float*)d_out);
}

// Round 16
// 358.976 us; speedup vs baseline: 1.0221x; 1.0181x over previous
//
#include <hip/hip_runtime.h>
#include <hip/hip_bf16.h>

#define NN 40000
#define NE 640000
#define NG 1000

typedef __attribute__((ext_vector_type(8))) short short8;
typedef __attribute__((ext_vector_type(4))) float f32x4;
typedef __attribute__((ext_vector_type(2))) __bf16 bf16x2v;

__device__ __forceinline__ float gelu_t(float x) {
    float u = 0.7978845608028654f * (x + 0.044715f * x * x * x);
    return 0.5f * x * (1.0f + tanhf(u));
}
__device__ __forceinline__ void atomAddF(float* p, float v) {
    unsafeAtomicAdd(p, v);
}
__device__ __forceinline__ int rfl(int v) { return __builtin_amdgcn_readfirstlane(v); }
__device__ __forceinline__ unsigned short f2bf(float f) {
    unsigned u = __float_as_uint(f);
    unsigned r = (u + 0x7fffu + ((u >> 16) & 1u)) >> 16;
    return (unsigned short)r;
}
__device__ __forceinline__ unsigned pk_bf(float lo, float hi) {
    __hip_bfloat162 v = __float22bfloat162_rn(make_float2(lo, hi));
    unsigned r;
    __builtin_memcpy(&r, &v, 4);
    return r;
}
__device__ __forceinline__ float bfl(unsigned p) { return __uint_as_float(p << 16); }
__device__ __forceinline__ float bfh(unsigned p) { return __uint_as_float(p & 0xffff0000u); }

__device__ __forceinline__ float dot2bf(unsigned a, unsigned b, float c) {
#if __has_builtin(__builtin_amdgcn_fdot2_f32_bf16)
    bf16x2v av, bv;
    __builtin_memcpy(&av, &a, 4);
    __builtin_memcpy(&bv, &b, 4);
    return __builtin_amdgcn_fdot2_f32_bf16(av, bv, c, false);
#else
    return c + bfl(a) * bfl(b) + bfh(a) * bfh(b);
#endif
}

// ---------------- Kernel P: x->bf16 + 8-way partitioned histogram + packs ----
__global__ __launch_bounds__(256) void k_pre(
    const float* __restrict__ x, const int* __restrict__ dst,
    const float* __restrict__ W_self, const float* __restrict__ W_msg,
    const float* __restrict__ W_e1, const float* __restrict__ b_msg,
    const float* __restrict__ b_e1,
    const float* __restrict__ W_l, const float* __restrict__ W_r,
    const float* __restrict__ W_e2,
    unsigned short* __restrict__ x_bf, int* __restrict__ hist,
    int* __restrict__ rank,
    unsigned short* __restrict__ wf1, unsigned short* __restrict__ wf2,
    unsigned* __restrict__ we2p, float* __restrict__ bsum2) {
    int t = blockIdx.x * 256 + threadIdx.x;
    float4 v = ((const float4*)x)[t];
    ((uint2*)x_bf)[t] = make_uint2(pk_bf(v.x, v.y), pk_bf(v.z, v.w));
    int part = t / 80000;           // 8 edge-range partitions
    rank[t] = atomicAdd(&hist[part * NN + dst[t]], 1);
    if (t < 256) bsum2[t] = b_msg[t] + b_e1[t];
    if (t < 5120) {
        int l = t & 63;
        int kt = (t >> 6) % 5;
        int gnt = t / 320;
        int n = gnt * 16 + (l & 15);
        int k0 = kt * 32 + (l >> 4) * 8;
        unsigned short vv[8];
        #pragma unroll
        for (int j = 0; j < 8; ++j) {
            int k = k0 + j;
            float wv;
            if (k < 64)       wv = W_self[(size_t)k * 256 + n];
            else if (k < 128) wv = W_msg[(size_t)(k - 64) * 256 + n];
            else if (k < 144) wv = W_e1[(size_t)(k - 128) * 256 + n];
            else              wv = 0.f;
            vv[j] = f2bf(wv);
        }
        uint4 pack;
        pack.x = (unsigned)vv[0] | ((unsigned)vv[1] << 16);
        pack.y = (unsigned)vv[2] | ((unsigned)vv[3] << 16);
        pack.z = (unsigned)vv[4] | ((unsigned)vv[5] << 16);
        pack.w = (unsigned)vv[6] | ((unsigned)vv[7] << 16);
        ((uint4*)wf1)[t] = pack;
    }
    if (t >= 5120 && t < 13312) {
        int t2 = t - 5120;
        int l = t2 & 63;
        int kt = (t2 >> 6) & 7;
        int gnt = t2 >> 9;
        int n = gnt * 16 + (l & 15);
        int k0 = kt * 32 + (l >> 4) * 8;
        const float* W = (n < 128) ? W_l : W_r;
        int nn = n & 127;
        float w[8];
        #pragma unroll
        for (int j = 0; j < 8; ++j) w[j] = W[(size_t)(k0 + j) * 128 + nn];
        uint4 pack;
        pack.x = pk_bf(w[0], w[1]);
        pack.y = pk_bf(w[2], w[3]);
        pack.z = pk_bf(w[4], w[5]);
        pack.w = pk_bf(w[6], w[7]);
        ((uint4*)wf2)[t2] = pack;
    }
    if (t >= 13312 && t < 14336) {
        int t3 = t - 13312;
        int tt = t3 >> 7;
        int c = t3 & 127;
        we2p[t3] = pk_bf(W_e2[(size_t)(2 * tt) * 128 + c],
                         W_e2[(size_t)(2 * tt + 1) * 128 + c]);
    }
}

// ---------------- CSR build: parallel degree sum (padded to 40960) -----------
__global__ __launch_bounds__(256) void k_dsum(const int* __restrict__ hist,
                                              int* __restrict__ dsum) {
    int idx = blockIdx.x * 256 + threadIdx.x;
    if (idx >= 40960) return;
    int s = 0;
    if (idx < NN) {
        #pragma unroll
        for (int p = 0; p < 8; ++p) s += hist[p * NN + idx];
    }
    dsum[idx] = s;
}

// ---------------- CSR build: single-block vectorized exclusive scan ----------
__global__ __launch_bounds__(1024) void k_scan(const int* __restrict__ dsum,
                                               int* __restrict__ row_ptr) {
    __shared__ int ssum[1024];
    int t = threadIdx.x;
    int base = t * 40;             // 1024*40 = 40960 exactly
    const int4* dv = (const int4*)(dsum + base);
    int local[40];
    int s = 0;
    #pragma unroll
    for (int j = 0; j < 10; ++j) {
        int4 v = dv[j];
        local[j * 4 + 0] = s; s += v.x;
        local[j * 4 + 1] = s; s += v.y;
        local[j * 4 + 2] = s; s += v.z;
        local[j * 4 + 3] = s; s += v.w;
    }
    ssum[t] = s;
    __syncthreads();
    for (int o = 1; o < 1024; o <<= 1) {
        int tmp = (t >= o) ? ssum[t - o] : 0;
        __syncthreads();
        ssum[t] += tmp;
        __syncthreads();
    }
    int prefix = (t > 0) ? ssum[t - 1] : 0;
    int4* rv = (int4*)(row_ptr + base);
    #pragma unroll
    for (int j = 0; j < 10; ++j) {
        int4 o4;
        o4.x = prefix + local[j * 4 + 0];
        o4.y = prefix + local[j * 4 + 1];
        o4.z = prefix + local[j * 4 + 2];
        o4.w = prefix + local[j * 4 + 3];
        rv[j] = o4;
    }
}

// ---------------- CSR build: per-partition offsets (parallel) ----------------
__global__ __launch_bounds__(256) void k_off(const int* __restrict__ hist,
                                             const int* __restrict__ row_ptr,
                                             int* __restrict__ off) {
    int idx = blockIdx.x * 256 + threadIdx.x;
    if (idx >= NN) return;
    int acc = row_ptr[idx];
    #pragma unroll
    for (int p = 0; p < 8; ++p) {
        off[p * NN + idx] = acc;
        acc += hist[p * NN + idx];
    }
}

// ---------------- CSR build: atomic-free scatter -----------------------------
__global__ __launch_bounds__(256) void k_scatter(const int* __restrict__ src,
                                                 const int* __restrict__ dst,
                                                 const int* __restrict__ rank,
                                                 const int* __restrict__ off,
                                                 const float* __restrict__ eattr,
                                                 int* __restrict__ csr_src,
                                                 unsigned short* __restrict__ ea_csr) {
    int e = blockIdx.x * 256 + threadIdx.x;
    if (e >= NE) return;
    int d = dst[e];
    int p = e / 80000;
    int pos = off[p * NN + d] + rank[e];
    csr_src[pos] = src[e];
    const float4* ep = (const float4*)(eattr + (size_t)e * 16);
    float4 a = ep[0], b = ep[1], c = ep[2], dd = ep[3];
    uint4 q0, q1;
    q0.x = pk_bf(a.x, a.y); q0.y = pk_bf(a.z, a.w);
    q0.z = pk_bf(b.x, b.y); q0.w = pk_bf(b.z, b.w);
    q1.x = pk_bf(c.x, c.y); q1.y = pk_bf(c.z, c.w);
    q1.z = pk_bf(dd.x, dd.y); q1.w = pk_bf(dd.z, dd.w);
    uint4* out = (uint4*)ea_csr;
    out[(size_t)pos * 2]     = q0;
    out[(size_t)pos * 2 + 1] = q1;
}

// ---------------- Kernel A: per-dst gather aggregation (quarter-wave) --------
__global__ __launch_bounds__(256) void k_agg(
    const unsigned short* __restrict__ x_bf, const unsigned short* __restrict__ ea_csr,
    const int* __restrict__ csr_src, const int* __restrict__ row_ptr,
    unsigned short* __restrict__ aggx_bf, unsigned short* __restrict__ aggea_bf,
    float* __restrict__ degf) {
    int d = rfl(blockIdx.x * 4 + (threadIdx.x >> 6));
    int lane = threadIdx.x & 63;
    if (d >= NN) return;
    int beg = row_ptr[d], end = row_ptr[d + 1];
    const uint2* xw2 = (const uint2*)x_bf;     // row = 16 uint2
    const unsigned* eaw = (const unsigned*)ea_csr;
    int q = lane >> 4;        // quarter 0..3
    int ql = lane & 15;       // lane-in-quarter: cols [4*ql, 4*ql+4)
    float s0a = 0.f, s1a = 0.f, s2a = 0.f, s3a = 0.f;
    float s0b = 0.f, s1b = 0.f, s2b = 0.f, s3b = 0.f;
    int i = beg;
    for (; i + 7 < end; i += 8) {
        int sA = csr_src[i + q];
        int sB = csr_src[i + 4 + q];
        uint2 wA = xw2[(size_t)sA * 16 + ql];
        uint2 wB = xw2[(size_t)sB * 16 + ql];
        s0a += bfl(wA.x); s1a += bfh(wA.x); s2a += bfl(wA.y); s3a += bfh(wA.y);
        s0b += bfl(wB.x); s1b += bfh(wB.x); s2b += bfl(wB.y); s3b += bfh(wB.y);
    }
    for (; i + q < end; i += 4) {
        int s = csr_src[i + q];
        uint2 w = xw2[(size_t)s * 16 + ql];
        s0a += bfl(w.x); s1a += bfh(w.x); s2a += bfl(w.y); s3a += bfh(w.y);
    }
    float sx0 = s0a + s0b, sx1 = s1a + s1b, sx2 = s2a + s2b, sx3 = s3a + s3b;
    sx0 += __shfl_xor(sx0, 16, 64); sx0 += __shfl_xor(sx0, 32, 64);
    sx1 += __shfl_xor(sx1, 16, 64); sx1 += __shfl_xor(sx1, 32, 64);
    sx2 += __shfl_xor(sx2, 16, 64); sx2 += __shfl_xor(sx2, 32, 64);
    sx3 += __shfl_xor(sx3, 16, 64); sx3 += __shfl_xor(sx3, 32, 64);
    // --- ea: flat sequential sum; uint p covers cols (2*(p&7), +1)
    float se0 = 0.f, se1 = 0.f, se0b = 0.f, se1b = 0.f;
    int p = beg * 8 + lane;
    int pend = end * 8;
    for (; p + 64 < pend; p += 128) {
        unsigned w = eaw[p];
        unsigned w2 = eaw[p + 64];
        se0 += bfl(w); se1 += bfh(w);
        se0b += bfl(w2); se1b += bfh(w2);
    }
    if (p < pend) {
        unsigned w = eaw[p];
        se0 += bfl(w); se1 += bfh(w);
    }
    se0 += se0b; se1 += se1b;
    #pragma unroll
    for (int off = 8; off < 64; off <<= 1) {
        se0 += __shfl_xor(se0, off, 64);
        se1 += __shfl_xor(se1, off, 64);
    }
    if (q == 0)
        ((uint2*)aggx_bf)[(size_t)d * 16 + ql] =
            make_uint2(pk_bf(sx0, sx1), pk_bf(sx2, sx3));
    if (lane < 8) ((unsigned*)aggea_bf)[(size_t)d * 8 + lane] = pk_bf(se0, se1);
    if (lane == 0) degf[d] = (float)(end - beg);
}

// ---------------- Kernel HX: fused h-GEMM + xl/xr-GEMM (MFMA, LDS-staged) ----
__global__ __launch_bounds__(256) void k_hx(
    const unsigned short* __restrict__ x_bf, const unsigned short* __restrict__ aggx_bf,
    const unsigned short* __restrict__ aggea_bf, const float* __restrict__ degf,
    const unsigned short* __restrict__ wf1, const unsigned short* __restrict__ wf2,
    const float* __restrict__ b_self, const float* __restrict__ bsum2,
    const float* __restrict__ b_l, const float* __restrict__ b_r,
    unsigned short* __restrict__ xl_bf, unsigned short* __restrict__ xr_bf) {
    __shared__ unsigned short hs[64][264];
    int w = threadIdx.x >> 6;
    int l = threadIdx.x & 63;
    int m0 = blockIdx.x * 64;
    int quad = l >> 4, lm = l & 15;
    {
        f32x4 acc[4][4] = {};
        short8 z8 = {0, 0, 0, 0, 0, 0, 0, 0};
        #pragma unroll
        for (int kt = 0; kt < 5; ++kt) {
            short8 a[4], b[4];
            #pragma unroll
            for (int mt = 0; mt < 4; ++mt) {
                int row = m0 + mt * 16 + lm;
                if (kt < 2)
                    a[mt] = *(const short8*)(x_bf + (size_t)row * 64 + kt * 32 + quad * 8);
                else if (kt < 4)
                    a[mt] = *(const short8*)(aggx_bf + (size_t)row * 64 + (kt - 2) * 32 + quad * 8);
                else
                    a[mt] = (quad < 2)
                        ? *(const short8*)(aggea_bf + (size_t)row * 16 + quad * 8)
                        : z8;
            }
            #pragma unroll
            for (int nt = 0; nt < 4; ++nt)
                b[nt] = *(const short8*)(wf1 + (((size_t)(w * 4 + nt) * 5 + kt) * 64 + l) * 8);
            #pragma unroll
            for (int mt = 0; mt < 4; ++mt)
                #pragma unroll
                for (int nt = 0; nt < 4; ++nt)
                    acc[mt][nt] = __builtin_amdgcn_mfma_f32_16x16x32_bf16(a[mt], b[nt], acc[mt][nt], 0, 0, 0);
        }
        #pragma unroll
        for (int nt = 0; nt < 4; ++nt) {
            int col = w * 64 + nt * 16 + lm;
            float bs = b_self[col];
            float b2 = bsum2[col];
            #pragma unroll
            for (int mt = 0; mt < 4; ++mt) {
                float4 dg = *(const float4*)(degf + m0 + mt * 16 + quad * 4);
                #pragma unroll
                for (int r = 0; r < 4; ++r) {
                    float v = gelu_t(acc[mt][nt][r] + bs + (&dg.x)[r] * b2);
                    hs[mt * 16 + quad * 4 + r][col] = f2bf(v);
                }
            }
        }
    }
    __syncthreads();
    f32x4 acc2[4][4] = {};
    #pragma unroll
    for (int kt = 0; kt < 8; ++kt) {
        short8 a[4], b[4];
        #pragma unroll
        for (int mt = 0; mt < 4; ++mt)
            a[mt] = *(const short8*)(&hs[mt * 16 + lm][kt * 32 + quad * 8]);
        #pragma unroll
        for (int nt = 0; nt < 4; ++nt)
            b[nt] = *(const short8*)(wf2 + (((size_t)(w * 4 + nt) * 8 + kt) * 64 + l) * 8);
        #pragma unroll
        for (int mt = 0; mt < 4; ++mt)
            #pragma unroll
            for (int nt = 0; nt < 4; ++nt)
                acc2[mt][nt] = __builtin_amdgcn_mfma_f32_16x16x32_bf16(a[mt], b[nt], acc2[mt][nt], 0, 0, 0);
    }
    bool isl = (w < 2);
    unsigned short* outp = isl ? xl_bf : xr_bf;
    int colbase = isl ? w * 64 : (w - 2) * 64;
    const float* bias = isl ? b_l : b_r;
    #pragma unroll
    for (int nt = 0; nt < 4; ++nt) {
        int col = colbase + nt * 16 + lm;
        float bv = bias[col];
        #pragma unroll
        for (int mt = 0; mt < 4; ++mt) {
            #pragma unroll
            for (int r = 0; r < 4; ++r) {
                int row = m0 + mt * 16 + quad * 4 + r;
                outp[(size_t)row * 128 + col] = f2bf(acc2[mt][nt][r] + bv);
            }
        }
    }
}

// ---------------- edge score helper (packed bf16 dot2) ------------------------
__device__ __forceinline__ float edge_score_pk(const unsigned* ep8,
                                               unsigned pl, float xr0, float xr1,
                                               const unsigned* wp0, const unsigned* wp1,
                                               float a0, float a1) {
    float m0 = bfl(pl) + xr0;
    float m1 = bfh(pl) + xr1;
    #pragma unroll
    for (int t = 0; t < 8; ++t) {
        m0 = dot2bf(ep8[t], wp0[t], m0);
        m1 = dot2bf(ep8[t], wp1[t], m1);
    }
    m0 = (m0 > 0.f) ? m0 : 0.2f * m0;
    m1 = (m1 > 0.f) ? m1 : 0.2f * m1;
    float part = m0 * a0 + m1 * a1;
    #pragma unroll
    for (int off = 32; off; off >>= 1) part += __shfl_xor(part, off, 64);
    return part;
}

__device__ __forceinline__ void online_upd(float al, unsigned p, float& m_run,
                                           float& l_run, float& n0, float& n1) {
    if (al > m_run) {
        float sc = __expf(m_run - al);
        l_run *= sc; n0 *= sc; n1 *= sc;
        m_run = al;
    }
    float wgt = __expf(al - m_run);
    l_run += wgt;
    n0 += wgt * bfl(p);
    n1 += wgt * bfh(p);
}

// ---------------- Kernel D: fused per-dst GATv2 (r10 proven body) ------------
__global__ __launch_bounds__(256) void k_gat(
    const unsigned* __restrict__ xlw, const unsigned* __restrict__ xrw,
    const unsigned short* __restrict__ ea_csr, const int* __restrict__ csr_src,
    const int* __restrict__ row_ptr, const unsigned short* __restrict__ aggea_bf,
    const unsigned* __restrict__ we2p, const float* __restrict__ att,
    const float* __restrict__ bias2, const int* __restrict__ batch,
    float* __restrict__ gsum, float* __restrict__ cnt) {
    int d = rfl(blockIdx.x * 4 + (threadIdx.x >> 6));
    int lane = threadIdx.x & 63;
    if (d >= NN) return;
    unsigned wp0[8], wp1[8];
    #pragma unroll
    for (int t = 0; t < 8; ++t) {
        uint2 wv = *(const uint2*)(we2p + t * 128 + 2 * lane);
        wp0[t] = wv.x; wp1[t] = wv.y;
    }
    float2 av = *(const float2*)(att + 2 * lane);
    float a0 = av.x, a1 = av.y;
    int beg = row_ptr[d], end = row_ptr[d + 1];
    const uint4* eap = (const uint4*)ea_csr;
    unsigned pld = xlw[(size_t)d * 64 + lane];
    unsigned prd = xrw[(size_t)d * 64 + lane];
    float xr0 = bfl(prd), xr1 = bfh(prd);
    float inv = 1.0f / fmaxf((float)(end - beg), 1.0f);
    float al_loop;
    {
        const uint4* ae = (const uint4*)(aggea_bf + (size_t)d * 16);
        uint4 q0 = ae[0], q1 = ae[1];
        unsigned ep8[8] = {q0.x, q0.y, q0.z, q0.w, q1.x, q1.y, q1.z, q1.w};
        float d0 = 0.f, d1 = 0.f;
        #pragma unroll
        for (int t = 0; t < 8; ++t) {
            d0 = dot2bf(ep8[t], wp0[t], d0);
            d1 = dot2bf(ep8[t], wp1[t], d1);
        }
        float m0 = bfl(pld) + xr0 + inv * d0;
        float m1 = bfh(pld) + xr1 + inv * d1;
        m0 = (m0 > 0.f) ? m0 : 0.2f * m0;
        m1 = (m1 > 0.f) ? m1 : 0.2f * m1;
        float part = m0 * a0 + m1 * a1;
        #pragma unroll
        for (int off = 32; off; off >>= 1) part += __shfl_xor(part, off, 64);
        al_loop = part;
    }
    float m_run = al_loop, l_run = 1.0f;
    float n0 = bfl(pld), n1 = bfh(pld);
    int i = beg;
    for (; i + 3 < end; i += 4) {
        int s0 = rfl(csr_src[i]),     s1 = rfl(csr_src[i + 1]);
        int s2 = rfl(csr_src[i + 2]), s3 = rfl(csr_src[i + 3]);
        uint4 qa0 = eap[(size_t)i * 2],       qa1 = eap[(size_t)i * 2 + 1];
        uint4 qb0 = eap[(size_t)(i + 1) * 2], qb1 = eap[(size_t)(i + 1) * 2 + 1];
        uint4 qc0 = eap[(size_t)(i + 2) * 2], qc1 = eap[(size_t)(i + 2) * 2 + 1];
        uint4 qd0 = eap[(size_t)(i + 3) * 2], qd1 = eap[(size_t)(i + 3) * 2 + 1];
        unsigned p0 = xlw[(size_t)s0 * 64 + lane];
        unsigned p1 = xlw[(size_t)s1 * 64 + lane];
        unsigned p2 = xlw[(size_t)s2 * 64 + lane];
        unsigned p3 = xlw[(size_t)s3 * 64 + lane];
        unsigned e0[8] = {qa0.x, qa0.y, qa0.z, qa0.w, qa1.x, qa1.y, qa1.z, qa1.w};
        unsigned e1[8] = {qb0.x, qb0.y, qb0.z, qb0.w, qb1.x, qb1.y, qb1.z, qb1.w};
        unsigned e2[8] = {qc0.x, qc0.y, qc0.z, qc0.w, qc1.x, qc1.y, qc1.z, qc1.w};
        unsigned e3[8] = {qd0.x, qd0.y, qd0.z, qd0.w, qd1.x, qd1.y, qd1.z, qd1.w};
        float al0 = edge_score_pk(e0, p0, xr0, xr1, wp0, wp1, a0, a1);
        float al1 = edge_score_pk(e1, p1, xr0, xr1, wp0, wp1, a0, a1);
        float al2 = edge_score_pk(e2, p2, xr0, xr1, wp0, wp1, a0, a1);
        float al3 = edge_score_pk(e3, p3, xr0, xr1, wp0, wp1, a0, a1);
        float gm = fmaxf(fmaxf(al0, al1), fmaxf(al2, al3));
        if (gm > m_run) {
            float sc = __expf(m_run - gm);
            l_run *= sc; n0 *= sc; n1 *= sc;
            m_run = gm;
        }
        float w0 = __expf(al0 - m_run);
        float w1 = __expf(al1 - m_run);
        float w2 = __expf(al2 - m_run);
        float w3 = __expf(al3 - m_run);
        l_run += (w0 + w1) + (w2 + w3);
        n0 += w0 * bfl(p0) + w1 * bfl(p1) + w2 * bfl(p2) + w3 * bfl(p3);
        n1 += w0 * bfh(p0) + w1 * bfh(p1) + w2 * bfh(p2) + w3 * bfh(p3);
    }
    for (; i < end; ++i) {
        int s = rfl(csr_src[i]);
        uint4 q0 = eap[(size_t)i * 2], q1 = eap[(size_t)i * 2 + 1];
        unsigned p = xlw[(size_t)s * 64 + lane];
        unsigned e8[8] = {q0.x, q0.y, q0.z, q0.w, q1.x, q1.y, q1.z, q1.w};
        float al = edge_score_pk(e8, p, xr0, xr1, wp0, wp1, a0, a1);
        online_upd(al, p, m_run, l_run, n0, n1);
    }
    float rinv = 1.0f / l_run;
    float2 bv = *(const float2*)(bias2 + 2 * lane);
    float o0 = n0 * rinv + bv.x;
    float o1 = n1 * rinv + bv.y;
    int g = batch[d];
    atomAddF(&gsum[(size_t)g * 128 + 2 * lane], o0);
    atomAddF(&gsum[(size_t)g * 128 + 2 * lane + 1], o1);
    if (lane == 0) atomAddF(&cnt[g], 1.0f);
}

// ---------------- Kernel G: FFN ----------------------------------------------
__global__ __launch_bounds__(256) void k_ffn(
    const float* __restrict__ gsum, const float* __restrict__ cnt,
    const float* __restrict__ W1, const float* __restrict__ b1,
    const float* __restrict__ W2, const float* __restrict__ b2,
    float* __restrict__ y) {
    __shared__ float row[128];
    __shared__ float red[4];
    int g = blockIdx.x;
    int t = threadIdx.x;
    if (t < 128) row[t] = gsum[(size_t)g * 128 + t] / fmaxf(cnt[g], 1.0f);
    __syncthreads();
    float part = 0.f;
    #pragma unroll
    for (int jj = 0; jj < 2; ++jj) {
        int j = t + jj * 256;
        float acc = b1[j];
        for (int k = 0; k < 128; ++k) acc += row[k] * W1[k * 512 + j];
        part += gelu_t(acc) * W2[j];
    }
    #pragma unroll
    for (int off = 32; off; off >>= 1) part += __shfl_xor(part, off, 64);
    if ((t & 63) == 0) red[t >> 6] = part;
    __syncthreads();
    if (t == 0) y[g] = red[0] + red[1] + red[2] + red[3] + b2[0];
}

extern "C" void kernel_launch(void* const* d_in, const int* in_sizes, int n_in,
                              void* d_out, int out_size, void* d_ws, size_t ws_size,
                              hipStream_t stream) {
    const float* x      = (const float*)d_in[0];
    const int*   eidx   = (const int*)d_in[1];
    const float* eattr  = (const float*)d_in[2];
    const int*   batch  = (const int*)d_in[3];
    const float* W_msg  = (const float*)d_in[4];
    const float* b_msg  = (const float*)d_in[5];
    const float* W_e1   = (const float*)d_in[6];
    const float* b_e1   = (const float*)d_in[7];
    const float* W_self = (const float*)d_in[8];
    const float* b_self = (const float*)d_in[9];
    const float* W_l    = (const float*)d_in[10];
    const float* b_l    = (const float*)d_in[11];
    const float* W_r    = (const float*)d_in[12];
    const float* b_r    = (const float*)d_in[13];
    const float* W_e2   = (const float*)d_in[14];
    const float* att    = (const float*)d_in[15];
    const float* bias2  = (const float*)d_in[16];
    const float* W1     = (const float*)d_in[17];
    const float* b1     = (const float*)d_in[18];
    const float* W2     = (const float*)d_in[19];
    const float* b2     = (const float*)d_in[20];
    const int* src = eidx;
    const int* dst = eidx + NE;

    char* wsb = (char*)d_ws;
    size_t o = 0;
    int*   hist   = (int*)(wsb + o);   o += (size_t)8 * NN * 4;   // 8 partitions
    float* gsum   = (float*)(wsb + o); o += (size_t)NG * 128 * 4;
    float* cnt    = (float*)(wsb + o); o += 4096;
    size_t zero_bytes = o;
    int*   dsum    = (int*)(wsb + o);  o += (size_t)40960 * 4;
    int*   row_ptr = (int*)(wsb + o);  o += (size_t)40964 * 4;
    int*   off     = (int*)(wsb + o);  o += (size_t)8 * NN * 4;
    int*   rank    = (int*)(wsb + o);  o += (size_t)NE * 4;
    int*   csr_src = (int*)(wsb + o);  o += (size_t)NE * 4;
    unsigned short* ea_csr = (unsigned short*)(wsb + o); o += (size_t)NE * 16 * 2;
    unsigned short* aggx_bf  = (unsigned short*)(wsb + o); o += (size_t)NN * 64 * 2;
    unsigned short* aggea_bf = (unsigned short*)(wsb + o); o += (size_t)NN * 16 * 2;
    float* degf    = (float*)(wsb + o); o += (size_t)NN * 4;
    unsigned short* x_bf  = (unsigned short*)(wsb + o); o += (size_t)NN * 64 * 2;
    unsigned short* xl_bf = (unsigned short*)(wsb + o); o += (size_t)NN * 128 * 2;
    unsigned short* xr_bf = (unsigned short*)(wsb + o); o += (size_t)NN * 128 * 2;
    unsigned short* wf1   = (unsigned short*)(wsb + o); o += (size_t)5120 * 8 * 2;
    unsigned short* wf2   = (unsigned short*)(wsb + o); o += (size_t)8192 * 8 * 2;
    unsigned* we2p = (unsigned*)(wsb + o); o += (size_t)1024 * 4;
    float* bsum2  = (float*)(wsb + o); o += 1024;

    hipMemsetAsync(d_ws, 0, zero_bytes, stream);
    hipLaunchKernelGGL(k_pre, dim3(2500), dim3(256), 0, stream,
                       x, dst, W_self, W_msg, W_e1, b_msg, b_e1, W_l, W_r, W_e2,
                       x_bf, hist, rank, wf1, wf2, we2p, bsum2);
    hipLaunchKernelGGL(k_dsum, dim3(160), dim3(256), 0, stream, hist, dsum);
    hipLaunchKernelGGL(k_scan, dim3(1), dim3(1024), 0, stream, dsum, row_ptr);
    hipLaunchKernelGGL(k_off, dim3((NN + 255) / 256), dim3(256), 0, stream,
                       hist, row_ptr, off);
    hipLaunchKernelGGL(k_scatter, dim3(2500), dim3(256), 0, stream,
                       src, dst, rank, off, eattr, csr_src, ea_csr);
    hipLaunchKernelGGL(k_agg, dim3((NN + 3) / 4), dim3(256), 0, stream,
                       x_bf, ea_csr, csr_src, row_ptr, aggx_bf, aggea_bf, degf);
    hipLaunchKernelGGL(k_hx, dim3(625), dim3(256), 0, stream,
                       x_bf, aggx_bf, aggea_bf, degf, wf1, wf2,
                       b_self, bsum2, b_l, b_r, xl_bf, xr_bf);
    hipLaunchKernelGGL(k_gat, dim3((NN + 3) / 4), dim3(256), 0, stream,
                       (const unsigned*)xl_bf, (const unsigned*)xr_bf, ea_csr,
                       csr_src, row_ptr, aggea_bf, we2p, att, bias2,
                       batch, gsum, cnt);
    hipLaunchKernelGGL(k_ffn, dim3(NG), dim3(256), 0, stream,
                       gsum, cnt, W1, b1, W2, b2, (float*)d_out);
}